// Round 1
// 1630.101 us; speedup vs baseline: 1.4055x; 1.4055x over previous
//
#include <hip/hip_runtime.h>
#include <stdint.h>
#include <stddef.h>

// ScannedRNN: SEQ=512 BATCH=128 D_IN=512 H=512
// Round 4: kill the per-step global h round-trip in k_scan.
//   - k_scan is now 512 threads (8 waves), TWO-PHASE per step:
//       phase A: every wave computes its full gate slice (acc[4mt][4zt][3p])
//       barrier -> phase B: epilogue updates h DIRECTLY in LDS (race-free,
//       all MFMA reads of the h tile finished at the barrier).
//   - h state lives in LDS as bf16 hi/lo pair (f32-accurate reconstruction,
//     hi is bit-identical to the old bf16 MFMA A path). No __threadfence,
//     no volatile reloads, no global hp reads: outputs is write-only (NT).
//   - G repacked by k_gates: z/r interleaved per column -> scan loads them
//     as one u32 (+u16 for n): 384 -> 128 G loads/thread/step, nontemporal.
// k_detect / k_starts / k_swz unchanged from round 3.

#define SEQ   512
#define BATCH 128
#define DIN   512
#define HD    512
#define G3    1536

typedef __attribute__((ext_vector_type(8))) short bf16x8;
typedef __attribute__((ext_vector_type(4))) float f32x4;

#define WS_FLAG_OFF   0
#define WS_STARTS_OFF 256
#define WS_SWZIN_OFF  131072
#define WS_SWZH_OFF   (131072 + 1572864)
#define WS_G_OFF      4194304          // 65536*1536*2B = 201.3MB

__device__ __forceinline__ unsigned short f2bf(float x){
  union { float f; unsigned u; } v; v.f = x;
  return (unsigned short)((v.u + 0x7FFFu + ((v.u >> 16) & 1u)) >> 16);
}
__device__ __forceinline__ float bf2f(unsigned short u){
  union { unsigned u; float f; } v; v.u = ((unsigned)u) << 16; return v.f;
}
__device__ __forceinline__ int get_reset(const void* r, int flag, int idx){
  return flag ? (((const int*)r)[idx] != 0)
              : (((const unsigned char*)r)[idx] != 0);
}
// XOR-swizzled 16B-chunk address for 64x512 bf16 A tile (row stride 1024B).
__device__ __forceinline__ int h_addr(int row, int kc){
  return row * 1024 + ((kc ^ (row & 7)) << 4);
}
__device__ __forceinline__ bf16x8 pack8(float4 a, float4 c){
  bf16x8 v;
  v[0]=(short)f2bf(a.x); v[1]=(short)f2bf(a.y); v[2]=(short)f2bf(a.z); v[3]=(short)f2bf(a.w);
  v[4]=(short)f2bf(c.x); v[5]=(short)f2bf(c.y); v[6]=(short)f2bf(c.z); v[7]=(short)f2bf(c.w);
  return v;
}

__global__ void k_detect(const int* resets, int* flag){
  __shared__ int bad;
  if (threadIdx.x == 0) bad = 0;
  __syncthreads();
  int ok = 1;
  for (int i = threadIdx.x; i < 4096; i += 256){
    int v = resets[i];
    if (v != 0 && v != 1) ok = 0;
  }
  if (!ok) atomicOr(&bad, 1);
  __syncthreads();
  if (threadIdx.x == 0) *flag = bad ? 0 : 1;
}

__global__ void k_starts(const void* resets, const int* flag, int* starts){
  int x = blockIdx.x * 256 + threadIdx.x;      // chunk id, 16384 total
  int b = x >> 7, c = x & 127;                 // 128 chunks per batch row, W=4
  int f = *flag;
  int t = 0;
  if (c != 0){
    t = c * 4;
    while (t < SEQ && !get_reset(resets, f, t * BATCH + b)) t++;
  }
  starts[x] = t;
}

__global__ void k_swz(const float* Win, const float* Wh,
                      unsigned short* swz_in, unsigned short* swz_h){
  int id = blockIdx.x * 256 + threadIdx.x;     // 2*96*16*64 = 196608
  int l  = id & 63; id >>= 6;
  int kt = id & 15; id >>= 4;
  int nt = id % 96; int which = id / 96;
  const float* W = which ? Wh : Win;
  unsigned short* o = which ? swz_h : swz_in;
  int kbase = kt * 32 + (l >> 4) * 8;
  int col   = nt * 16 + (l & 15);
  bf16x8 v;
#pragma unroll
  for (int j = 0; j < 8; ++j) v[j] = (short)f2bf(W[(size_t)(kbase + j) * G3 + col]);
  ((bf16x8*)o)[(size_t)(nt * 16 + kt) * 64 + l] = v;
}

__launch_bounds__(256, 1)
__global__ void k_gates(const float* ins, const float* b_in,
                        const unsigned short* swzW, unsigned short* G){
  __shared__ unsigned short hA[64 * 512];      // 64KB, swizzled
  const int tid = threadIdx.x;
  const int row0 = blockIdx.x * 64;
#pragma unroll
  for (int i = 0; i < 16; ++i){
    int cid = i * 256 + tid;                   // 4096 16B chunks
    int r = cid >> 6, kc = cid & 63;
    const float* src = ins + (size_t)(row0 + r) * DIN + kc * 8;
    float4 a = ((const float4*)src)[0];
    float4 c = ((const float4*)src)[1];
    *(bf16x8*)((char*)hA + h_addr(r, kc)) = pack8(a, c);
  }
  __syncthreads();
  const int lane = tid & 63, w = tid >> 6;
  const int quad = lane >> 4, lm = lane & 15;
  for (int itn = 0; itn < 4; ++itn){           // wave covers nt [24w, 24w+24)
    int ntb = w * 24 + itn * 6;
    f32x4 acc[4][6];
#pragma unroll
    for (int mt = 0; mt < 4; ++mt)
#pragma unroll
      for (int n = 0; n < 6; ++n) acc[mt][n] = (f32x4){0.f,0.f,0.f,0.f};
    for (int kt = 0; kt < 16; ++kt){
      bf16x8 a[4];
#pragma unroll
      for (int mt = 0; mt < 4; ++mt)
        a[mt] = *(bf16x8*)((char*)hA + h_addr(mt * 16 + lm, kt * 4 + quad));
#pragma unroll
      for (int n = 0; n < 6; ++n){
        bf16x8 bfr = ((const bf16x8*)swzW)[(size_t)((ntb + n) * 16 + kt) * 64 + lane];
#pragma unroll
        for (int mt = 0; mt < 4; ++mt)
          acc[mt][n] = __builtin_amdgcn_mfma_f32_16x16x32_bf16(a[mt], bfr, acc[mt][n], 0, 0, 0);
      }
    }
#pragma unroll
    for (int n = 0; n < 6; ++n){
      int col = (ntb + n) * 16 + lm;
      float bias = b_in[col];
      // repack: z/r interleaved per hidden col, n tail. part uniform per n-iter.
      int part = col >> 9;
      int c = col & 511;
      size_t off = (part < 2) ? (size_t)(2 * c + part) : (size_t)(1024 + c);
#pragma unroll
      for (int mt = 0; mt < 4; ++mt){
        int gr = row0 + mt * 16 + quad * 4;
#pragma unroll
        for (int r = 0; r < 4; ++r)
          G[(size_t)(gr + r) * G3 + off] = f2bf(acc[mt][n][r] + bias);
      }
    }
  }
}

__launch_bounds__(512, 2)
__global__ void k_scan(const void* resets, const int* flag, const int* starts,
                       const unsigned short* swz_h, const unsigned short* G,
                       float* out_final, float* outputs){
  __shared__ unsigned short hHi[64 * 512];     // 64KB bf16 high part (MFMA A tile)
  __shared__ unsigned short hLo[64 * 512];     // 64KB bf16 low-correction (hp = hi+lo)
  const int tid = threadIdx.x, lane = tid & 63, w = tid >> 6;   // w in [0,8)
  const int quad = lane >> 4, lm = lane & 15;
  const int g = blockIdx.x;
  const int b = g >> 1;
  const int f = *flag;
  const int chunk = g * 64 + lane;             // every lane = one walker row
  const int t_start = starts[chunk];
  const int t_end = ((chunk & 127) == 127) ? SEQ : starts[chunk + 1];
  int t_cur = t_start;

  for (int i = tid; i < 4096; i += 512){
    bf16x8 z;
#pragma unroll
    for (int j = 0; j < 8; ++j) z[j] = 0;
    *(bf16x8*)((char*)hHi + h_addr(i >> 6, i & 63)) = z;
    *(bf16x8*)((char*)hLo + h_addr(i >> 6, i & 63)) = z;
  }
  __syncthreads();

  const bf16x8* Bp = (const bf16x8*)swz_h + lane;

  for (int guard = 0; guard < SEQ + 8; ++guard){
    bool active = t_cur < t_end;
    unsigned long long bal_act = __ballot(active);
    if (bal_act == 0ull) break;
    int t_next = active ? t_cur + 1 : t_cur;
    bool rstn = active && (t_next < t_end) && get_reset(resets, f, t_next * BATCH + b);
    unsigned long long bal_rstn = __ballot(rstn);

    // ---- phase A: full-step MFMA. wave w owns zt in [4w, 4w+4) ----
    f32x4 acc[4][4][3];                        // [mt][z][part], 192 VGPRs
#pragma unroll
    for (int mt = 0; mt < 4; ++mt)
#pragma unroll
      for (int z = 0; z < 4; ++z)
#pragma unroll
        for (int p = 0; p < 3; ++p) acc[mt][z][p] = (f32x4){0.f,0.f,0.f,0.f};

    for (int kt = 0; kt < 16; ++kt){
      bf16x8 ah[4];
#pragma unroll
      for (int mt = 0; mt < 4; ++mt)
        ah[mt] = *(bf16x8*)((char*)hHi + h_addr(mt * 16 + lm, kt * 4 + quad));
#pragma unroll
      for (int z = 0; z < 4; ++z){
        int zt = w * 4 + z;
        bf16x8 B0 = Bp[((size_t)(zt)      * 16 + kt) * 64];
        bf16x8 B1 = Bp[((size_t)(32 + zt) * 16 + kt) * 64];
        bf16x8 B2 = Bp[((size_t)(64 + zt) * 16 + kt) * 64];
#pragma unroll
        for (int mt = 0; mt < 4; ++mt){
          acc[mt][z][0] = __builtin_amdgcn_mfma_f32_16x16x32_bf16(ah[mt], B0, acc[mt][z][0], 0,0,0);
          acc[mt][z][1] = __builtin_amdgcn_mfma_f32_16x16x32_bf16(ah[mt], B1, acc[mt][z][1], 0,0,0);
          acc[mt][z][2] = __builtin_amdgcn_mfma_f32_16x16x32_bf16(ah[mt], B2, acc[mt][z][2], 0,0,0);
        }
      }
    }
    __syncthreads();   // all MFMA reads of hHi are done -> epilogue may write h in-place

    // ---- phase B: gate math + direct LDS h update (thread-private slots) ----
    int ts_q[16];
#pragma unroll
    for (int mt = 0; mt < 4; ++mt)
#pragma unroll
      for (int r = 0; r < 4; ++r)
        ts_q[mt * 4 + r] = __shfl(t_cur, mt * 16 + quad * 4 + r, 64);

#pragma unroll
    for (int mt = 0; mt < 4; ++mt){
#pragma unroll
      for (int r = 0; r < 4; ++r){
        int s = mt * 16 + quad * 4 + r;
        if (!((bal_act >> s) & 1ull)) continue;
        int ts = ts_q[mt * 4 + r];
        bool rz = (bal_rstn >> s) & 1ull;
        size_t gb = ((size_t)ts * BATCH + b) * G3;
        size_t ob = ((size_t)ts * BATCH + b) * HD;
#pragma unroll
        for (int z = 0; z < 4; ++z){
          int col = (w * 4 + z) * 16 + lm;
          unsigned zr = __builtin_nontemporal_load((const unsigned*)(G + gb + col * 2));
          unsigned short gnv = __builtin_nontemporal_load(G + gb + 1024 + col);
          float zg = 1.f / (1.f + __expf(-(bf2f((unsigned short)(zr & 0xFFFFu)) + acc[mt][z][0][r])));
          float rg = 1.f / (1.f + __expf(-(bf2f((unsigned short)(zr >> 16))     + acc[mt][z][1][r])));
          float pre = bf2f(gnv) + rg * acc[mt][z][2][r];
          float e = __expf(-2.f * fabsf(pre));
          float nn = copysignf((1.f - e) / (1.f + e), pre);
          char* hiP = (char*)hHi + h_addr(s, col >> 3) + (col & 7) * 2;
          char* loP = (char*)hLo + h_addr(s, col >> 3) + (col & 7) * 2;
          float hp = bf2f(*(unsigned short*)hiP) + bf2f(*(unsigned short*)loP);
          float hn = (1.f - zg) * nn + zg * hp;
          __builtin_nontemporal_store(hn, outputs + ob + col);
          if (ts == SEQ - 1) out_final[(size_t)b * HD + col] = hn;
          unsigned short nh = 0, nl = 0;
          if (!rz){
            nh = f2bf(hn);
            nl = f2bf(hn - bf2f(nh));
          }
          *(unsigned short*)hiP = nh;
          *(unsigned short*)loP = nl;
        }
      }
    }
    t_cur = t_next;
    __syncthreads();   // h updates visible before next step's MFMA reads
  }
}

extern "C" void kernel_launch(void* const* d_in, const int* in_sizes, int n_in,
                              void* d_out, int out_size, void* d_ws, size_t ws_size,
                              hipStream_t stream) {
  const float* ins   = (const float*)d_in[1];
  const void*  rsts  = d_in[2];
  const float* W_in  = (const float*)d_in[3];
  const float* b_in  = (const float*)d_in[4];
  const float* W_h   = (const float*)d_in[5];

  char* ws = (char*)d_ws;
  int* flag            = (int*)(ws + WS_FLAG_OFF);
  int* starts          = (int*)(ws + WS_STARTS_OFF);
  unsigned short* swzi = (unsigned short*)(ws + WS_SWZIN_OFF);
  unsigned short* swzh = (unsigned short*)(ws + WS_SWZH_OFF);
  unsigned short* G    = (unsigned short*)(ws + WS_G_OFF);

  float* out_final = (float*)d_out;                  // (128,512)
  float* outputs   = (float*)d_out + BATCH * HD;     // (512,128,512)

  k_detect<<<1, 256, 0, stream>>>((const int*)rsts, flag);
  k_starts<<<64, 256, 0, stream>>>(rsts, flag, starts);
  k_swz<<<768, 256, 0, stream>>>(W_in, W_h, swzi, swzh);
  k_gates<<<1024, 256, 0, stream>>>(ins, b_in, swzi, G);
  k_scan<<<256, 512, 0, stream>>>(rsts, flag, starts, swzh, G, out_final, outputs);
}

// Round 3
// 1504.939 us; speedup vs baseline: 1.5224x; 1.0832x over previous
//
#include <hip/hip_runtime.h>
#include <stdint.h>
#include <stddef.h>

// ScannedRNN: SEQ=512 BATCH=128 D_IN=512 H=512
// Round 6: round-5 structure with the phase-B pipeline WAR bug fixed.
//   Round-5 bug: "ISSUE(J+4); COMPUTE(J);" overwrote the rolling buffer
//   slot (J&3) BEFORE COMPUTE(J) consumed it -> 12/16 slots used the wrong
//   timestep's gates (absmax 1.97). Fix: 8-deep rolling buffer, prefetch
//   slots 0..7 before phase A (lands under MFMA), then COMPUTE(J); ISSUE(J+8)
//   so every buffer is consumed before overwrite, and late loads retain
//   ~8 compute-slots of latency cover.
//   - G repacked (by k_gates) so scan reads per slot ONE dwordx4 (z|r pairs
//     for the 4 z-cols of a (wave,lane)) + ONE dwordx2 (n for 4 cols):
//     32 loads/thread/step instead of 128, fully coalesced.
//     Layout per row (u16 units, row stride 1536):
//       Z region [0,1024): u32[(w*16+lm)*4+z] = (r_gate<<16)|z_gate, col=(w*4+z)*16+lm
//       N region [1024,1536): u16[1024 + (w*16+lm)*4+z] = n_gate
//   - rstn ballot sunk to after phase A.
//   - k_gates: 512 threads, M=128 rows/block (128KB LDS), 2 n-groups of 6.
// h state stays LDS-resident bf16 hi/lo (round-4 validated structure).

#define SEQ   512
#define BATCH 128
#define DIN   512
#define HD    512
#define G3    1536

typedef __attribute__((ext_vector_type(8))) short bf16x8;
typedef __attribute__((ext_vector_type(4))) float f32x4;
typedef __attribute__((ext_vector_type(4))) unsigned int u32x4;
typedef __attribute__((ext_vector_type(2))) unsigned int u32x2;

#define WS_FLAG_OFF   0
#define WS_STARTS_OFF 256
#define WS_SWZIN_OFF  131072
#define WS_SWZH_OFF   (131072 + 1572864)
#define WS_G_OFF      4194304          // 65536*1536*2B = 201.3MB

__device__ __forceinline__ unsigned short f2bf(float x){
  union { float f; unsigned u; } v; v.f = x;
  return (unsigned short)((v.u + 0x7FFFu + ((v.u >> 16) & 1u)) >> 16);
}
__device__ __forceinline__ float bf2f(unsigned short u){
  union { unsigned u; float f; } v; v.u = ((unsigned)u) << 16; return v.f;
}
__device__ __forceinline__ int get_reset(const void* r, int flag, int idx){
  return flag ? (((const int*)r)[idx] != 0)
              : (((const unsigned char*)r)[idx] != 0);
}
// XOR-swizzled 16B-chunk address for [rows]x512 bf16 A tile (row stride 1024B).
__device__ __forceinline__ int h_addr(int row, int kc){
  return row * 1024 + ((kc ^ (row & 7)) << 4);
}
__device__ __forceinline__ bf16x8 pack8(float4 a, float4 c){
  bf16x8 v;
  v[0]=(short)f2bf(a.x); v[1]=(short)f2bf(a.y); v[2]=(short)f2bf(a.z); v[3]=(short)f2bf(a.w);
  v[4]=(short)f2bf(c.x); v[5]=(short)f2bf(c.y); v[6]=(short)f2bf(c.z); v[7]=(short)f2bf(c.w);
  return v;
}

__global__ void k_detect(const int* resets, int* flag){
  __shared__ int bad;
  if (threadIdx.x == 0) bad = 0;
  __syncthreads();
  int ok = 1;
  for (int i = threadIdx.x; i < 4096; i += 256){
    int v = resets[i];
    if (v != 0 && v != 1) ok = 0;
  }
  if (!ok) atomicOr(&bad, 1);
  __syncthreads();
  if (threadIdx.x == 0) *flag = bad ? 0 : 1;
}

__global__ void k_starts(const void* resets, const int* flag, int* starts){
  int x = blockIdx.x * 256 + threadIdx.x;      // chunk id, 16384 total
  int b = x >> 7, c = x & 127;                 // 128 chunks per batch row, W=4
  int f = *flag;
  int t = 0;
  if (c != 0){
    t = c * 4;
    while (t < SEQ && !get_reset(resets, f, t * BATCH + b)) t++;
  }
  starts[x] = t;
}

__global__ void k_swz(const float* Win, const float* Wh,
                      unsigned short* swz_in, unsigned short* swz_h){
  int id = blockIdx.x * 256 + threadIdx.x;     // 2*96*16*64 = 196608
  int l  = id & 63; id >>= 6;
  int kt = id & 15; id >>= 4;
  int nt = id % 96; int which = id / 96;
  const float* W = which ? Wh : Win;
  unsigned short* o = which ? swz_h : swz_in;
  int kbase = kt * 32 + (l >> 4) * 8;
  int col   = nt * 16 + (l & 15);
  bf16x8 v;
#pragma unroll
  for (int j = 0; j < 8; ++j) v[j] = (short)f2bf(W[(size_t)(kbase + j) * G3 + col]);
  ((bf16x8*)o)[(size_t)(nt * 16 + kt) * 64 + l] = v;
}

__launch_bounds__(512, 1)
__global__ void k_gates(const float* ins, const float* b_in,
                        const unsigned short* swzW, unsigned short* G){
  __shared__ unsigned short hA[128 * 512];     // 128KB, swizzled
  const int tid = threadIdx.x;
  const int row0 = blockIdx.x * 128;
#pragma unroll
  for (int i = 0; i < 16; ++i){
    int cid = i * 512 + tid;                   // 8192 16B chunks
    int r = cid >> 6, kc = cid & 63;
    const float* src = ins + (size_t)(row0 + r) * DIN + kc * 8;
    float4 a = ((const float4*)src)[0];
    float4 c = ((const float4*)src)[1];
    *(bf16x8*)((char*)hA + h_addr(r, kc)) = pack8(a, c);
  }
  __syncthreads();
  const int lane = tid & 63, w = tid >> 6;
  const int quad = lane >> 4, lm = lane & 15;
  for (int itn = 0; itn < 2; ++itn){           // wave covers nt [12w, 12w+12)
    int ntb = w * 12 + itn * 6;
    f32x4 acc[8][6];
#pragma unroll
    for (int mt = 0; mt < 8; ++mt)
#pragma unroll
      for (int n = 0; n < 6; ++n) acc[mt][n] = (f32x4){0.f,0.f,0.f,0.f};
    for (int kt = 0; kt < 16; ++kt){
      bf16x8 a[8];
#pragma unroll
      for (int mt = 0; mt < 8; ++mt)
        a[mt] = *(bf16x8*)((char*)hA + h_addr(mt * 16 + lm, kt * 4 + quad));
#pragma unroll
      for (int n = 0; n < 6; ++n){
        bf16x8 bfr = ((const bf16x8*)swzW)[(size_t)((ntb + n) * 16 + kt) * 64 + lane];
#pragma unroll
        for (int mt = 0; mt < 8; ++mt)
          acc[mt][n] = __builtin_amdgcn_mfma_f32_16x16x32_bf16(a[mt], bfr, acc[mt][n], 0, 0, 0);
      }
    }
#pragma unroll
    for (int n = 0; n < 6; ++n){
      int col = (ntb + n) * 16 + lm;
      float bias = b_in[col];
      // map col -> repacked offset (see header comment)
      int part = col >> 9;
      int c = col & 511;
      int nt16 = c >> 4, clm = c & 15;
      int slot = (((nt16 >> 2) * 16 + clm) << 2) + (nt16 & 3);
      int off = (part < 2) ? (2 * slot + part) : (1024 + slot);
#pragma unroll
      for (int mt = 0; mt < 8; ++mt){
        int gr = row0 + mt * 16 + quad * 4;
#pragma unroll
        for (int r = 0; r < 4; ++r)
          G[(size_t)(gr + r) * G3 + off] = f2bf(acc[mt][n][r] + bias);
      }
    }
  }
}

__launch_bounds__(512, 2)
__global__ void k_scan(const void* resets, const int* flag, const int* starts,
                       const unsigned short* swz_h, const unsigned short* G,
                       float* out_final, float* outputs){
  __shared__ unsigned short hHi[64 * 512];     // 64KB bf16 high part (MFMA A tile)
  __shared__ unsigned short hLo[64 * 512];     // 64KB bf16 low-correction (hp = hi+lo)
  const int tid = threadIdx.x, lane = tid & 63, w = tid >> 6;   // w in [0,8)
  const int quad = lane >> 4, lm = lane & 15;
  const int g = blockIdx.x;
  const int b = g >> 1;
  const int f = *flag;
  const int chunk = g * 64 + lane;             // every lane = one walker row
  const int t_start = starts[chunk];
  const int t_end = ((chunk & 127) == 127) ? SEQ : starts[chunk + 1];
  int t_cur = t_start;
  const int wl = w * 16 + lm;

  for (int i = tid; i < 4096; i += 512){
    bf16x8 z;
#pragma unroll
    for (int j = 0; j < 8; ++j) z[j] = 0;
    *(bf16x8*)((char*)hHi + h_addr(i >> 6, i & 63)) = z;
    *(bf16x8*)((char*)hLo + h_addr(i >> 6, i & 63)) = z;
  }
  __syncthreads();

  const bf16x8* Bw = (const bf16x8*)swz_h + lane;

  for (int guard = 0; guard < SEQ + 8; ++guard){
    bool active = t_cur < t_end;
    unsigned long long bal_act = __ballot(active);
    if (bal_act == 0ull) break;
    int t_next = active ? t_cur + 1 : t_cur;
    // reset load issues here; its ballot (and wait) is sunk past phase A
    bool rstn = active && (t_next < t_end) && get_reset(resets, f, t_next * BATCH + b);

    // slot timesteps (uniform control flow shfl)
    int ts_q[16];
#pragma unroll
    for (int mt = 0; mt < 4; ++mt)
#pragma unroll
      for (int r = 0; r < 4; ++r)
        ts_q[mt * 4 + r] = __shfl(t_cur, mt * 16 + quad * 4 + r, 64);

    u32x4 zrB[8];
    u32x2 nB[8];
#define ISSUE(J) do {                                                          \
      int ts_ = ts_q[J]; ts_ = ts_ < (SEQ - 1) ? ts_ : (SEQ - 1);              \
      const unsigned short* gp_ = G + ((size_t)ts_ * BATCH + b) * G3;          \
      zrB[(J) & 7] = __builtin_nontemporal_load((const u32x4*)gp_ + wl);       \
      nB[(J) & 7]  = __builtin_nontemporal_load((const u32x2*)(gp_ + 1024) + wl); \
    } while (0)

    // prefetch first 8 slots' gates: lands during the MFMA phase
    ISSUE(0); ISSUE(1); ISSUE(2); ISSUE(3);
    ISSUE(4); ISSUE(5); ISSUE(6); ISSUE(7);

    // ---- phase A: full-step MFMA. wave w owns zt in [4w, 4w+4) ----
    f32x4 acc[4][4][3];                        // [mt][z][part]
#pragma unroll
    for (int mt = 0; mt < 4; ++mt)
#pragma unroll
      for (int z = 0; z < 4; ++z)
#pragma unroll
        for (int p = 0; p < 3; ++p) acc[mt][z][p] = (f32x4){0.f,0.f,0.f,0.f};

    for (int kt = 0; kt < 16; ++kt){
      bf16x8 ah[4];
#pragma unroll
      for (int mt = 0; mt < 4; ++mt)
        ah[mt] = *(bf16x8*)((char*)hHi + h_addr(mt * 16 + lm, kt * 4 + quad));
#pragma unroll
      for (int z = 0; z < 4; ++z){
        int idx = ((w * 4 + z) * 16 + kt) << 6;
        bf16x8 B0 = Bw[idx];
        bf16x8 B1 = Bw[idx + 32768];           // +32*16*64
        bf16x8 B2 = Bw[idx + 65536];           // +64*16*64
#pragma unroll
        for (int mt = 0; mt < 4; ++mt){
          acc[mt][z][0] = __builtin_amdgcn_mfma_f32_16x16x32_bf16(ah[mt], B0, acc[mt][z][0], 0,0,0);
          acc[mt][z][1] = __builtin_amdgcn_mfma_f32_16x16x32_bf16(ah[mt], B1, acc[mt][z][1], 0,0,0);
          acc[mt][z][2] = __builtin_amdgcn_mfma_f32_16x16x32_bf16(ah[mt], B2, acc[mt][z][2], 0,0,0);
        }
      }
    }
    __syncthreads();   // all MFMA reads of hHi done -> epilogue may write h in-place

    unsigned long long bal_rstn = __ballot(rstn);   // wait lands here, post-MFMA

    // ---- phase B: gate math + direct LDS h update, 8-deep pipelined ----
    // Buffer discipline: COMPUTE(J) consumes buf (J&7) BEFORE ISSUE(J+8)
    // overwrites it (round-5 bug was the reverse order).
#define COMPUTE(J) do {                                                        \
      const int mt_ = (J) >> 2, r_ = (J) & 3;                                  \
      const int s_ = mt_ * 16 + quad * 4 + r_;                                 \
      if ((bal_act >> s_) & 1ull){                                             \
        int ts_ = ts_q[J];                                                     \
        bool rz_ = (bal_rstn >> s_) & 1ull;                                    \
        size_t ob_ = ((size_t)ts_ * BATCH + b) * HD;                           \
        u32x4 zr_ = zrB[(J) & 7];                                              \
        u32x2 nn_ = nB[(J) & 7];                                               \
        _Pragma("unroll")                                                      \
        for (int z = 0; z < 4; ++z){                                           \
          int col = (w * 4 + z) * 16 + lm;                                     \
          unsigned zru = zr_[z];                                               \
          unsigned short gnv = (unsigned short)((z & 1) ? (nn_[z >> 1] >> 16)  \
                                                        : (nn_[z >> 1] & 0xFFFFu)); \
          float zg = 1.f / (1.f + __expf(-(bf2f((unsigned short)(zru & 0xFFFFu)) + acc[mt_][z][0][r_]))); \
          float rg = 1.f / (1.f + __expf(-(bf2f((unsigned short)(zru >> 16))     + acc[mt_][z][1][r_]))); \
          float pre = bf2f(gnv) + rg * acc[mt_][z][2][r_];                     \
          float e = __expf(-2.f * fabsf(pre));                                 \
          float nnv = copysignf((1.f - e) / (1.f + e), pre);                   \
          char* hiP = (char*)hHi + h_addr(s_, col >> 3) + (col & 7) * 2;       \
          char* loP = (char*)hLo + h_addr(s_, col >> 3) + (col & 7) * 2;       \
          float hp = bf2f(*(unsigned short*)hiP) + bf2f(*(unsigned short*)loP);\
          float hn = (1.f - zg) * nnv + zg * hp;                               \
          __builtin_nontemporal_store(hn, outputs + ob_ + col);                \
          if (ts_ == SEQ - 1) out_final[(size_t)b * HD + col] = hn;            \
          unsigned short nh = 0, nl = 0;                                       \
          if (!rz_){ nh = f2bf(hn); nl = f2bf(hn - bf2f(nh)); }                \
          *(unsigned short*)hiP = nh;                                          \
          *(unsigned short*)loP = nl;                                          \
        }                                                                      \
      }                                                                        \
    } while (0)

    COMPUTE(0);  ISSUE(8);
    COMPUTE(1);  ISSUE(9);
    COMPUTE(2);  ISSUE(10);
    COMPUTE(3);  ISSUE(11);
    COMPUTE(4);  ISSUE(12);
    COMPUTE(5);  ISSUE(13);
    COMPUTE(6);  ISSUE(14);
    COMPUTE(7);  ISSUE(15);
    COMPUTE(8);  COMPUTE(9);  COMPUTE(10); COMPUTE(11);
    COMPUTE(12); COMPUTE(13); COMPUTE(14); COMPUTE(15);
#undef ISSUE
#undef COMPUTE

    t_cur = t_next;
    __syncthreads();   // h updates visible before next step's MFMA reads
  }
}

extern "C" void kernel_launch(void* const* d_in, const int* in_sizes, int n_in,
                              void* d_out, int out_size, void* d_ws, size_t ws_size,
                              hipStream_t stream) {
  const float* ins   = (const float*)d_in[1];
  const void*  rsts  = d_in[2];
  const float* W_in  = (const float*)d_in[3];
  const float* b_in  = (const float*)d_in[4];
  const float* W_h   = (const float*)d_in[5];

  char* ws = (char*)d_ws;
  int* flag            = (int*)(ws + WS_FLAG_OFF);
  int* starts          = (int*)(ws + WS_STARTS_OFF);
  unsigned short* swzi = (unsigned short*)(ws + WS_SWZIN_OFF);
  unsigned short* swzh = (unsigned short*)(ws + WS_SWZH_OFF);
  unsigned short* G    = (unsigned short*)(ws + WS_G_OFF);

  float* out_final = (float*)d_out;                  // (128,512)
  float* outputs   = (float*)d_out + BATCH * HD;     // (512,128,512)

  k_detect<<<1, 256, 0, stream>>>((const int*)rsts, flag);
  k_starts<<<64, 256, 0, stream>>>(rsts, flag, starts);
  k_swz<<<768, 256, 0, stream>>>(W_in, W_h, swzi, swzh);
  k_gates<<<512, 512, 0, stream>>>(ins, b_in, swzi, G);
  k_scan<<<256, 512, 0, stream>>>(rsts, flag, starts, swzh, G, out_final, outputs);
}

// Round 7
// 1295.774 us; speedup vs baseline: 1.7682x; 1.1614x over previous
//
#include <hip/hip_runtime.h>
#include <stdint.h>
#include <stddef.h>

// ScannedRNN: SEQ=512 BATCH=128 D_IN=512 H=512
// Round 10: round-7 algorithm, k_sched reshaped 1024->256 threads.
//   Rounds 7/8/9 all died at container level (no pytest output) while
//   rounds 0-3 ran fine; the only novel launch config in round 7 was the
//   1024-thread k_sched workgroup. This round removes that sole novelty;
//   k_scan / k_gates are UNCHANGED from round 7 (audited in-bounds,
//   barrier-uniform, prefix-invariant sound).
// Round 7: load-balanced walker scheduling + prefix block-skip in k_scan.
//   - k_sched: counting-sort all 16384 walks by length desc; WG g gets
//     16-row blocks {g, g+256, g+512, g+768}. Lane active for exactly
//     len steps from step 0 => active set is a monotone PREFIX => whole
//     blocks retire in order (block mt's shortest >= block mt+1's longest).
//   - k_scan: per-step nact = #active blocks (wave-uniform); scalar-guard
//     ah loads / MFMAs / acc init / phase-B per block. Walkers carry
//     per-lane (b, t_start, t_end) from sched; per-slot (ts, b) via
//     uniform-flow __shfl of a packed word.
//   - G pipeline 4-deep: COMPUTE(J) consumes buf (J&3) before ISSUE(J+4)
//     overwrites it. h state stays LDS-resident bf16 hi/lo.

#define SEQ   512
#define BATCH 128
#define DIN   512
#define HD    512
#define G3    1536

typedef __attribute__((ext_vector_type(8))) short bf16x8;
typedef __attribute__((ext_vector_type(4))) float f32x4;
typedef __attribute__((ext_vector_type(4))) unsigned int u32x4;
typedef __attribute__((ext_vector_type(2))) unsigned int u32x2;

#define WS_FLAG_OFF   0
#define WS_STARTS_OFF 256                      // 16384*4 = 65536
#define WS_SCHED_OFF  65792                    // 16384*4 = 65536 -> ends 131328
#define WS_SWZIN_OFF  131584                   // 1572864 -> ends 1704448
#define WS_SWZH_OFF   1704448                  // 1572864 -> ends 3277312
#define WS_G_OFF      4194304                  // 65536*1536*2B = 201.3MB

__device__ __forceinline__ unsigned short f2bf(float x){
  union { float f; unsigned u; } v; v.f = x;
  return (unsigned short)((v.u + 0x7FFFu + ((v.u >> 16) & 1u)) >> 16);
}
__device__ __forceinline__ float bf2f(unsigned short u){
  union { unsigned u; float f; } v; v.u = ((unsigned)u) << 16; return v.f;
}
__device__ __forceinline__ int get_reset(const void* r, int flag, int idx){
  return flag ? (((const int*)r)[idx] != 0)
              : (((const unsigned char*)r)[idx] != 0);
}
// XOR-swizzled 16B-chunk address for [rows]x512 bf16 A tile (row stride 1024B).
__device__ __forceinline__ int h_addr(int row, int kc){
  return row * 1024 + ((kc ^ (row & 7)) << 4);
}
__device__ __forceinline__ bf16x8 pack8(float4 a, float4 c){
  bf16x8 v;
  v[0]=(short)f2bf(a.x); v[1]=(short)f2bf(a.y); v[2]=(short)f2bf(a.z); v[3]=(short)f2bf(a.w);
  v[4]=(short)f2bf(c.x); v[5]=(short)f2bf(c.y); v[6]=(short)f2bf(c.z); v[7]=(short)f2bf(c.w);
  return v;
}

__global__ void k_detect(const int* resets, int* flag){
  __shared__ int bad;
  if (threadIdx.x == 0) bad = 0;
  __syncthreads();
  int ok = 1;
  for (int i = threadIdx.x; i < 4096; i += 256){
    int v = resets[i];
    if (v != 0 && v != 1) ok = 0;
  }
  if (!ok) atomicOr(&bad, 1);
  __syncthreads();
  if (threadIdx.x == 0) *flag = bad ? 0 : 1;
}

__global__ void k_starts(const void* resets, const int* flag, int* starts){
  int x = blockIdx.x * 256 + threadIdx.x;      // chunk id, 16384 total
  int b = x >> 7, c = x & 127;                 // 128 chunks per batch row, W=4
  int f = *flag;
  int t = 0;
  if (c != 0){
    t = c * 4;
    while (t < SEQ && !get_reset(resets, f, t * BATCH + b)) t++;
  }
  starts[x] = t;
}

// Counting-sort walks by length (descending) into sched[16384].
// rec = (b<<20) | (t_start<<10) | t_end   (b<128, fields <=512 fit 10 bits)
// 256 threads (round 10: was 1024 — the only novel launch shape of the
// failing rounds; algorithm unchanged).
__launch_bounds__(256)
__global__ void k_sched(const int* starts, unsigned* sched){
  __shared__ int hist[513];
  __shared__ int off[513];
  const int tid = threadIdx.x;                 // 256 threads
  for (int i = tid; i < 513; i += 256) hist[i] = 0;
  __syncthreads();
  for (int i = tid; i < 16384; i += 256){
    int c = i & 127;
    int ts = starts[i];
    int te = (c == 127) ? SEQ : starts[i + 1];
    atomicAdd(&hist[te - ts], 1);
  }
  __syncthreads();
  if (tid == 0){
    int acc = 0;
    for (int l = 512; l >= 0; --l){ off[l] = acc; acc += hist[l]; }
  }
  __syncthreads();
  for (int i = tid; i < 16384; i += 256){
    int b = i >> 7, c = i & 127;
    int ts = starts[i];
    int te = (c == 127) ? SEQ : starts[i + 1];
    int pos = atomicAdd(&off[te - ts], 1);
    sched[pos] = ((unsigned)b << 20) | ((unsigned)ts << 10) | (unsigned)te;
  }
}

__global__ void k_swz(const float* Win, const float* Wh,
                      unsigned short* swz_in, unsigned short* swz_h){
  int id = blockIdx.x * 256 + threadIdx.x;     // 2*96*16*64 = 196608
  int l  = id & 63; id >>= 6;
  int kt = id & 15; id >>= 4;
  int nt = id % 96; int which = id / 96;
  const float* W = which ? Wh : Win;
  unsigned short* o = which ? swz_h : swz_in;
  int kbase = kt * 32 + (l >> 4) * 8;
  int col   = nt * 16 + (l & 15);
  bf16x8 v;
#pragma unroll
  for (int j = 0; j < 8; ++j) v[j] = (short)f2bf(W[(size_t)(kbase + j) * G3 + col]);
  ((bf16x8*)o)[(size_t)(nt * 16 + kt) * 64 + l] = v;
}

__launch_bounds__(512, 1)
__global__ void k_gates(const float* ins, const float* b_in,
                        const unsigned short* swzW, unsigned short* G){
  __shared__ unsigned short hA[128 * 512];     // 128KB, swizzled
  const int tid = threadIdx.x;
  const int row0 = blockIdx.x * 128;
#pragma unroll
  for (int i = 0; i < 16; ++i){
    int cid = i * 512 + tid;                   // 8192 16B chunks
    int r = cid >> 6, kc = cid & 63;
    const float* src = ins + (size_t)(row0 + r) * DIN + kc * 8;
    float4 a = ((const float4*)src)[0];
    float4 c = ((const float4*)src)[1];
    *(bf16x8*)((char*)hA + h_addr(r, kc)) = pack8(a, c);
  }
  __syncthreads();
  const int lane = tid & 63, w = tid >> 6;
  const int quad = lane >> 4, lm = lane & 15;
  for (int itn = 0; itn < 2; ++itn){           // wave covers nt [12w, 12w+12)
    int ntb = w * 12 + itn * 6;
    f32x4 acc[8][6];
#pragma unroll
    for (int mt = 0; mt < 8; ++mt)
#pragma unroll
      for (int n = 0; n < 6; ++n) acc[mt][n] = (f32x4){0.f,0.f,0.f,0.f};
    for (int kt = 0; kt < 16; ++kt){
      bf16x8 a[8];
#pragma unroll
      for (int mt = 0; mt < 8; ++mt)
        a[mt] = *(bf16x8*)((char*)hA + h_addr(mt * 16 + lm, kt * 4 + quad));
#pragma unroll
      for (int n = 0; n < 6; ++n){
        bf16x8 bfr = ((const bf16x8*)swzW)[(size_t)((ntb + n) * 16 + kt) * 64 + lane];
#pragma unroll
        for (int mt = 0; mt < 8; ++mt)
          acc[mt][n] = __builtin_amdgcn_mfma_f32_16x16x32_bf16(a[mt], bfr, acc[mt][n], 0, 0, 0);
      }
    }
#pragma unroll
    for (int n = 0; n < 6; ++n){
      int col = (ntb + n) * 16 + lm;
      float bias = b_in[col];
      // map col -> repacked offset (z/r interleaved, n tail)
      int part = col >> 9;
      int c = col & 511;
      int nt16 = c >> 4, clm = c & 15;
      int slot = (((nt16 >> 2) * 16 + clm) << 2) + (nt16 & 3);
      int off = (part < 2) ? (2 * slot + part) : (1024 + slot);
#pragma unroll
      for (int mt = 0; mt < 8; ++mt){
        int gr = row0 + mt * 16 + quad * 4;
#pragma unroll
        for (int r = 0; r < 4; ++r)
          G[(size_t)(gr + r) * G3 + off] = f2bf(acc[mt][n][r] + bias);
      }
    }
  }
}

__launch_bounds__(512, 2)
__global__ void k_scan(const void* resets, const int* flag, const unsigned* sched,
                       const unsigned short* swz_h, const unsigned short* G,
                       float* out_final, float* outputs){
  __shared__ unsigned short hHi[64 * 512];     // 64KB bf16 high part (MFMA A tile)
  __shared__ unsigned short hLo[64 * 512];     // 64KB bf16 low-correction (hp = hi+lo)
  const int tid = threadIdx.x, lane = tid & 63, w = tid >> 6;   // w in [0,8)
  const int quad = lane >> 4, lm = lane & 15;
  const int g = blockIdx.x;
  const int f = *flag;
  // lane's walker from the sorted schedule: WG g, block mt = lane>>4 is
  // sorted block (g + 256*mt); row within block = lane&15.
  const unsigned rec = sched[((g + 256 * (lane >> 4)) << 4) + (lane & 15)];
  const int bw      = rec >> 20;
  const int t_start = (rec >> 10) & 1023;
  const int t_end   = rec & 1023;
  int t_cur = t_start;
  const int wl = w * 16 + lm;

  for (int i = tid; i < 4096; i += 512){
    bf16x8 z;
#pragma unroll
    for (int j = 0; j < 8; ++j) z[j] = 0;
    *(bf16x8*)((char*)hHi + h_addr(i >> 6, i & 63)) = z;
    *(bf16x8*)((char*)hLo + h_addr(i >> 6, i & 63)) = z;
  }
  __syncthreads();

  const bf16x8* Bw = (const bf16x8*)swz_h + lane;

  for (int guard = 0; guard < SEQ + 8; ++guard){
    bool active = t_cur < t_end;
    unsigned long long bal_act = __ballot(active);
    if (bal_act == 0ull) break;
    // monotone prefix: #active 16-row blocks (wave-uniform scalar)
    const int nact = (bal_act >> 48) ? 4 : (bal_act >> 32) ? 3 : (bal_act >> 16) ? 2 : 1;
    int t_next = active ? t_cur + 1 : t_cur;
    // reset load issues here; ballot (and wait) sunk past phase A
    bool rstn = active && (t_next < t_end) && get_reset(resets, f, t_next * BATCH + bw);
    // packed (b, ts) for cross-lane pickup in uniform control flow
    const int pk = (bw << 10) | (t_cur & 1023);

    u32x4 zrB[4];
    u32x2 nB[4];
#define SLOT(J) (((J) >> 2) * 16 + quad * 4 + ((J) & 3))
#define ISSUE(J) do {                                                          \
      if (nact > ((J) >> 2)){                                                  \
        int pk_ = __shfl(pk, SLOT(J), 64);                                     \
        int ts_ = pk_ & 1023; ts_ = ts_ < (SEQ - 1) ? ts_ : (SEQ - 1);         \
        int b_  = pk_ >> 10;                                                   \
        const unsigned short* gp_ = G + ((size_t)ts_ * BATCH + b_) * G3;       \
        zrB[(J) & 3] = __builtin_nontemporal_load((const u32x4*)gp_ + wl);     \
        nB[(J) & 3]  = __builtin_nontemporal_load((const u32x2*)(gp_ + 1024) + wl); \
      }                                                                        \
    } while (0)

    // prefetch first 4 slots' gates: lands during the MFMA phase
    ISSUE(0); ISSUE(1); ISSUE(2); ISSUE(3);

    // ---- phase A: MFMA over active prefix blocks. wave w owns zt [4w,4w+4) ----
    f32x4 acc[4][4][3];                        // [mt][z][part]
#pragma unroll
    for (int mt = 0; mt < 4; ++mt)
      if (nact > mt)
#pragma unroll
        for (int z = 0; z < 4; ++z)
#pragma unroll
          for (int p = 0; p < 3; ++p) acc[mt][z][p] = (f32x4){0.f,0.f,0.f,0.f};

    for (int kt = 0; kt < 16; ++kt){
      bf16x8 ah[4];
      ah[0] = *(bf16x8*)((char*)hHi + h_addr(lm, kt * 4 + quad));
      if (nact > 1) ah[1] = *(bf16x8*)((char*)hHi + h_addr(16 + lm, kt * 4 + quad));
      if (nact > 2) ah[2] = *(bf16x8*)((char*)hHi + h_addr(32 + lm, kt * 4 + quad));
      if (nact > 3) ah[3] = *(bf16x8*)((char*)hHi + h_addr(48 + lm, kt * 4 + quad));
#pragma unroll
      for (int z = 0; z < 4; ++z){
        int idx = ((w * 4 + z) * 16 + kt) << 6;
        bf16x8 B0 = Bw[idx];
        bf16x8 B1 = Bw[idx + 32768];           // +32*16*64
        bf16x8 B2 = Bw[idx + 65536];           // +64*16*64
        acc[0][z][0] = __builtin_amdgcn_mfma_f32_16x16x32_bf16(ah[0], B0, acc[0][z][0], 0,0,0);
        acc[0][z][1] = __builtin_amdgcn_mfma_f32_16x16x32_bf16(ah[0], B1, acc[0][z][1], 0,0,0);
        acc[0][z][2] = __builtin_amdgcn_mfma_f32_16x16x32_bf16(ah[0], B2, acc[0][z][2], 0,0,0);
        if (nact > 1){
          acc[1][z][0] = __builtin_amdgcn_mfma_f32_16x16x32_bf16(ah[1], B0, acc[1][z][0], 0,0,0);
          acc[1][z][1] = __builtin_amdgcn_mfma_f32_16x16x32_bf16(ah[1], B1, acc[1][z][1], 0,0,0);
          acc[1][z][2] = __builtin_amdgcn_mfma_f32_16x16x32_bf16(ah[1], B2, acc[1][z][2], 0,0,0);
        }
        if (nact > 2){
          acc[2][z][0] = __builtin_amdgcn_mfma_f32_16x16x32_bf16(ah[2], B0, acc[2][z][0], 0,0,0);
          acc[2][z][1] = __builtin_amdgcn_mfma_f32_16x16x32_bf16(ah[2], B1, acc[2][z][1], 0,0,0);
          acc[2][z][2] = __builtin_amdgcn_mfma_f32_16x16x32_bf16(ah[2], B2, acc[2][z][2], 0,0,0);
        }
        if (nact > 3){
          acc[3][z][0] = __builtin_amdgcn_mfma_f32_16x16x32_bf16(ah[3], B0, acc[3][z][0], 0,0,0);
          acc[3][z][1] = __builtin_amdgcn_mfma_f32_16x16x32_bf16(ah[3], B1, acc[3][z][1], 0,0,0);
          acc[3][z][2] = __builtin_amdgcn_mfma_f32_16x16x32_bf16(ah[3], B2, acc[3][z][2], 0,0,0);
        }
      }
    }
    __syncthreads();   // all MFMA reads of hHi done -> epilogue may write h in-place

    unsigned long long bal_rstn = __ballot(rstn);   // wait lands here, post-MFMA

    // ---- phase B: gate math + direct LDS h update, 4-deep pipelined ----
    // COMPUTE(J) consumes buf (J&3) BEFORE ISSUE(J+4) overwrites it.
#define COMPUTE(J) do {                                                        \
      if (nact > ((J) >> 2)){                                                  \
        const int mt_ = (J) >> 2, r_ = (J) & 3;                                \
        const int s_ = mt_ * 16 + quad * 4 + r_;                               \
        int pk_ = __shfl(pk, s_, 64);          /* uniform-flow shfl */         \
        if ((bal_act >> s_) & 1ull){                                           \
          int ts_ = pk_ & 1023, b_ = pk_ >> 10;                                \
          bool rz_ = (bal_rstn >> s_) & 1ull;                                  \
          size_t ob_ = ((size_t)ts_ * BATCH + b_) * HD;                        \
          u32x4 zr_ = zrB[(J) & 3];                                            \
          u32x2 nn_ = nB[(J) & 3];                                             \
          _Pragma("unroll")                                                    \
          for (int z = 0; z < 4; ++z){                                         \
            int col = (w * 4 + z) * 16 + lm;                                   \
            unsigned zru = zr_[z];                                             \
            unsigned short gnv = (unsigned short)((z & 1) ? (nn_[z >> 1] >> 16)\
                                                          : (nn_[z >> 1] & 0xFFFFu)); \
            float zg = 1.f / (1.f + __expf(-(bf2f((unsigned short)(zru & 0xFFFFu)) + acc[mt_][z][0][r_]))); \
            float rg = 1.f / (1.f + __expf(-(bf2f((unsigned short)(zru >> 16))     + acc[mt_][z][1][r_]))); \
            float pre = bf2f(gnv) + rg * acc[mt_][z][2][r_];                   \
            float e = __expf(-2.f * fabsf(pre));                               \
            float nnv = copysignf((1.f - e) / (1.f + e), pre);                 \
            char* hiP = (char*)hHi + h_addr(s_, col >> 3) + (col & 7) * 2;     \
            char* loP = (char*)hLo + h_addr(s_, col >> 3) + (col & 7) * 2;     \
            float hp = bf2f(*(unsigned short*)hiP) + bf2f(*(unsigned short*)loP); \
            float hn = (1.f - zg) * nnv + zg * hp;                             \
            __builtin_nontemporal_store(hn, outputs + ob_ + col);              \
            if (ts_ == SEQ - 1) out_final[(size_t)b_ * HD + col] = hn;         \
            unsigned short nh = 0, nl = 0;                                     \
            if (!rz_){ nh = f2bf(hn); nl = f2bf(hn - bf2f(nh)); }              \
            *(unsigned short*)hiP = nh;                                        \
            *(unsigned short*)loP = nl;                                        \
          }                                                                    \
        }                                                                      \
      }                                                                        \
    } while (0)

    COMPUTE(0);  ISSUE(4);
    COMPUTE(1);  ISSUE(5);
    COMPUTE(2);  ISSUE(6);
    COMPUTE(3);  ISSUE(7);
    COMPUTE(4);  ISSUE(8);
    COMPUTE(5);  ISSUE(9);
    COMPUTE(6);  ISSUE(10);
    COMPUTE(7);  ISSUE(11);
    COMPUTE(8);  ISSUE(12);
    COMPUTE(9);  ISSUE(13);
    COMPUTE(10); ISSUE(14);
    COMPUTE(11); ISSUE(15);
    COMPUTE(12); COMPUTE(13); COMPUTE(14); COMPUTE(15);
#undef ISSUE
#undef COMPUTE
#undef SLOT

    t_cur = t_next;
    __syncthreads();   // h updates visible before next step's MFMA reads
  }
}

extern "C" void kernel_launch(void* const* d_in, const int* in_sizes, int n_in,
                              void* d_out, int out_size, void* d_ws, size_t ws_size,
                              hipStream_t stream) {
  const float* ins   = (const float*)d_in[1];
  const void*  rsts  = d_in[2];
  const float* W_in  = (const float*)d_in[3];
  const float* b_in  = (const float*)d_in[4];
  const float* W_h   = (const float*)d_in[5];

  char* ws = (char*)d_ws;
  int* flag            = (int*)(ws + WS_FLAG_OFF);
  int* starts          = (int*)(ws + WS_STARTS_OFF);
  unsigned* sched      = (unsigned*)(ws + WS_SCHED_OFF);
  unsigned short* swzi = (unsigned short*)(ws + WS_SWZIN_OFF);
  unsigned short* swzh = (unsigned short*)(ws + WS_SWZH_OFF);
  unsigned short* G    = (unsigned short*)(ws + WS_G_OFF);

  float* out_final = (float*)d_out;                  // (128,512)
  float* outputs   = (float*)d_out + BATCH * HD;     // (512,128,512)

  k_detect<<<1, 256, 0, stream>>>((const int*)rsts, flag);
  k_starts<<<64, 256, 0, stream>>>(rsts, flag, starts);
  k_sched<<<1, 256, 0, stream>>>(starts, sched);
  k_swz<<<768, 256, 0, stream>>>(W_in, W_h, swzi, swzh);
  k_gates<<<512, 512, 0, stream>>>(ins, b_in, swzi, G);
  k_scan<<<256, 512, 0, stream>>>(rsts, flag, sched, swzh, G, out_final, outputs);
}